// Round 7
// baseline (148.828 us; speedup 1.0000x reference)
//
#include <hip/hip_runtime.h>

// Locally-connected conv (BioConvolution): per-patch GEMM
//   Z[n,p,o] = sum_k X_patch[n,p,k] * F[p,k,o],  K=512, N=FOUT=32, P=1024
//   A = relu(Z + bias)
// Round-6 structure (1024 blocks x 4 waves; wave w = K-quarter w = patch row;
// 4x 16x16 tiles per wave; 16 KiB LDS cross-wave reduce) but the load path is
// INLINE ASM: 20 global loads per k-step issued into asm-pinned register
// banks, counted s_waitcnt vmcnt(N) (never a mid-loop drain), sched_barrier
// after each wait. Two banks, 2-deep: 40+ loads in flight per wave at all
// times -> per-CU MLP ~16x round 6. The compiler can no longer collapse it.

typedef __attribute__((ext_vector_type(4))) float f32x4;
typedef __attribute__((ext_vector_type(8))) short s16x8;

#define HWC (128 * 128 * 32)   // per-batch X stride (floats)
#define WC  (128 * 32)         // per-row X stride (floats)

// --- asm load primitives: dest regs are pinned, offsets are literals ---
#define GLX4(dst, addr, OFF) \
    asm volatile("global_load_dwordx4 %0, %1, off offset:" OFF \
                 : "=v"(dst) : "v"(addr))
#define GL1(dst, addr, OFF) \
    asm volatile("global_load_dword %0, %1, off offset:" OFF \
                 : "=v"(dst) : "v"(addr))
// counted wait + scheduler fence (rule #18: VALU consumers must not hoist)
#define WAITV(N) do { \
    asm volatile("s_waitcnt vmcnt(" #N ")" ::: "memory"); \
    __builtin_amdgcn_sched_barrier(0); \
} while (0)

struct Bank {                 // 32 VGPRs of in-flight data
    f32x4 a00, a01, a10, a11; // A frags: [n-half][lo/hi 16B]
    float b0[8], b1[8];       // B frags: [o-half][j]
};

// A loads for one k-step: offsets OFF0 = ks*128, OFF1 = ks*128+16 (bytes)
#define GLA(K, A0, A1, OFF0, OFF1) do { \
    GLX4((K).a00, A0, OFF0); GLX4((K).a01, A0, OFF1); \
    GLX4((K).a10, A1, OFF0); GLX4((K).a11, A1, OFF1); \
} while (0)
// B loads for one k-step: Bq = B + ks*1024 floats; offsets j*128 / j*128+64
#define GLB(K, Bq) do { \
    GL1((K).b0[0], Bq, "0");   GL1((K).b1[0], Bq, "64");  \
    GL1((K).b0[1], Bq, "128"); GL1((K).b1[1], Bq, "192"); \
    GL1((K).b0[2], Bq, "256"); GL1((K).b1[2], Bq, "320"); \
    GL1((K).b0[3], Bq, "384"); GL1((K).b1[3], Bq, "448"); \
    GL1((K).b0[4], Bq, "512"); GL1((K).b1[4], Bq, "576"); \
    GL1((K).b0[5], Bq, "640"); GL1((K).b1[5], Bq, "704"); \
    GL1((K).b0[6], Bq, "768"); GL1((K).b1[6], Bq, "832"); \
    GL1((K).b0[7], Bq, "896"); GL1((K).b1[7], Bq, "960"); \
} while (0)

__device__ __forceinline__ short f2bf(float f) {
    unsigned u = __builtin_bit_cast(unsigned, f);
    u += 0x7fffu + ((u >> 16) & 1u);
    return (short)(u >> 16);
}
__device__ __forceinline__ s16x8 pack8(const f32x4 lo, const f32x4 hi) {
    s16x8 r;
    r[0] = f2bf(lo[0]); r[1] = f2bf(lo[1]); r[2] = f2bf(lo[2]); r[3] = f2bf(lo[3]);
    r[4] = f2bf(hi[0]); r[5] = f2bf(hi[1]); r[6] = f2bf(hi[2]); r[7] = f2bf(hi[3]);
    return r;
}
__device__ __forceinline__ s16x8 pack8f(const float* b) {
    s16x8 r;
    #pragma unroll
    for (int j = 0; j < 8; ++j) r[j] = f2bf(b[j]);
    return r;
}

__launch_bounds__(256, 4)
__global__ void lcconv_kernel(const float* __restrict__ X,
                              const float* __restrict__ F,
                              const float* __restrict__ bias,
                              float* __restrict__ out) {
    __shared__ f32x4 red[4][4][64];   // 16 KiB

    const int p    = blockIdx.x;
    const int pr   = p >> 5;
    const int pc   = p & 31;
    const int tid  = threadIdx.x;
    const int lane = tid & 63;
    const int w    = tid >> 6;        // wave = K-quarter = patch row i
    const int col  = lane & 15;
    const int g    = lane >> 4;

    const float* A0p = X + col * HWC + (pr * 4 + w) * WC + pc * 128 + g * 8;
    const float* A1p = A0p + 16 * HWC;
    const float* Bp  = F + p * (512 * 32) + (w * 128 + g * 8) * 32 + col;

    const int nh = w >> 1, oh = w & 1;
    const float* biasp = bias + (oh * 16 + col);

    Bank kA, kB;
    float bv;
    f32x4 acc00{0,0,0,0}, acc01{0,0,0,0}, acc10{0,0,0,0}, acc11{0,0,0,0};

    auto compute = [&](Bank& K) {
        s16x8 A0 = pack8(K.a00, K.a01);
        s16x8 A1 = pack8(K.a10, K.a11);
        s16x8 B0 = pack8f(K.b0);
        s16x8 B1 = pack8f(K.b1);
        acc00 = __builtin_amdgcn_mfma_f32_16x16x32_bf16(A0, B0, acc00, 0, 0, 0);
        acc01 = __builtin_amdgcn_mfma_f32_16x16x32_bf16(A0, B1, acc01, 0, 0, 0);
        acc10 = __builtin_amdgcn_mfma_f32_16x16x32_bf16(A1, B0, acc10, 0, 0, 0);
        acc11 = __builtin_amdgcn_mfma_f32_16x16x32_bf16(A1, B1, acc11, 0, 0, 0);
    };

    // ---- issue schedule (outstanding counts in comments) ----
    GL1(bv, biasp, "0");              //  1
    GLA(kA, A0p, A1p, "0", "16");     //  5
    GLB(kA, Bp);                      // 21
    GLA(kB, A0p, A1p, "128", "144");  // 25
    GLB(kB, (Bp + 1024));             // 41

    WAITV(20);                        // bias + k0 complete (k1 in flight)
    compute(kA);                      // k0
    GLA(kA, A0p, A1p, "256", "272");  // 24
    GLB(kA, (Bp + 2048));             // 40

    WAITV(20);                        // k1 complete (k2 in flight)
    compute(kB);                      // k1
    GLA(kB, A0p, A1p, "384", "400");  // 24
    GLB(kB, (Bp + 3072));             // 40

    WAITV(20);                        // k2 complete (k3 in flight)
    compute(kA);                      // k2

    WAITV(0);                         // k3 complete
    compute(kB);                      // k3

    // ---- cross-wave K reduction ----
    red[w][0][lane] = acc00;
    red[w][1][lane] = acc01;
    red[w][2][lane] = acc10;
    red[w][3][lane] = acc11;
    __syncthreads();

    f32x4 s  = red[0][w][lane];
    f32x4 t1 = red[1][w][lane];
    f32x4 t2 = red[2][w][lane];
    f32x4 t3 = red[3][w][lane];
    s += t1; s += t2; s += t3;

    // C/D layout: col o = lane&15, row n = (lane>>4)*4 + reg
    const int o_g = oh * 16 + col;
    #pragma unroll
    for (int r = 0; r < 4; ++r) {
        int n_g = nh * 16 + g * 4 + r;
        float v = s[r] + bv;
        v = v > 0.f ? v : 0.f;
        out[n_g * (1024 * 32) + p * 32 + o_g] = v;
    }
}

extern "C" void kernel_launch(void* const* d_in, const int* in_sizes, int n_in,
                              void* d_out, int out_size, void* d_ws, size_t ws_size,
                              hipStream_t stream) {
    const float* X    = (const float*)d_in[0];
    const float* F    = (const float*)d_in[1];
    const float* bias = (const float*)d_in[2];
    float* out        = (float*)d_out;
    lcconv_kernel<<<dim3(1024), dim3(256), 0, stream>>>(X, F, bias, out);
}